// Round 5
// baseline (182.292 us; speedup 1.0000x reference)
//
#include <hip/hip_runtime.h>
#include <math.h>

#define Bn 16
#define Ln 2048
#define Gn 8
#define Pn 8
#define Kn 64
#define CLAMP_V 15.0f

#define BPB 16              // blocks per batch -> grid = Bn*BPB = 256 blocks
#define NTH 1024            // threads per block = 16 waves
#define NWV (NTH / 64)      // 16 waves
#define LPB (Ln / BPB)      // 128 l's per block
#define LPW (LPB / NWV)     // 8 l's per wave

// d_ws layout: drms[Gn][Bn][Pn] floats, then cnt[Gn][Bn] ints (zeroed by init_ws).

__global__ __launch_bounds__(256) void init_ws(float* __restrict__ drms,
                                               int* __restrict__ cnt) {
    const int i = threadIdx.x;
    for (int j = i; j < Gn * Bn * Pn; j += 256) drms[j] = 0.0f;
    if (i < Gn * Bn) cnt[i] = 0;
}

// wave64 sum via DPP (VALU pipe, no LDS). Total lands in lane 63.
__device__ __forceinline__ float wave_sum64(float x) {
#define DPP_ADD(ctrl) \
    x += __int_as_float(__builtin_amdgcn_update_dpp(0, __float_as_int(x), ctrl, 0xf, 0xf, true))
    DPP_ADD(0x111);  // row_shr:1
    DPP_ADD(0x112);  // row_shr:2
    DPP_ADD(0x114);  // row_shr:4
    DPP_ADD(0x118);  // row_shr:8
    DPP_ADD(0x142);  // row_bcast:15
    DPP_ADD(0x143);  // row_bcast:31
#undef DPP_ADD
    return x;
}

// ---------------------------------------------------------------------------
// Whole scan in one kernel; per-batch 16-block barrier with RELAXED agent
// atomics (no fences -> no wbl2/inv storms; ordering via the vmcnt drain the
// compiler emits at __syncthreads).
// Inner loop is pure VALU: lane k keeps x_pred[a0[k]] and the 8 permuted
// x_nat points in REGISTERS (24 VGPRs); per (p,l):
//   (dp-dn)^2 = dp2 + dn2 - 2*sqrt(dp2*dn2)  -> 1 sqrt + ~11 VALU, 0 LDS.
// (round-4's 8 ds_bpermute/l serialized on the CU-shared LDS pipe with 5M
// conflict cycles; VALU sits on 4 SIMDs and runs 4x wider.)
// Reductions use DPP (VALU) instead of __shfl (LDS ds_bpermute).
// ---------------------------------------------------------------------------
__global__ __launch_bounds__(NTH) void fused_kernel(
    const float* __restrict__ xpred, const float* __restrict__ xnat,
    const int* __restrict__ mask_in, const int* __restrict__ autom,
    float* __restrict__ out_x, float* __restrict__ out_m,
    float* __restrict__ drms, int* __restrict__ cnt) {

    const int tid  = threadIdx.x;
    const int lane = tid & 63;       // k
    const int wv   = tid >> 6;       // wave 0..15
    const int b    = blockIdx.x >> 4;
    const int c    = blockIdx.x & (BPB - 1);

    __shared__ int    s_idx[Ln];       // private permutation: xnat row map
    __shared__ float4 s_xp[LPB];       // x_pred columns for this block
    __shared__ float4 s_xn[LPB];       // current x_nat columns (per group)
    __shared__ float  s_part[NWV][Pn];
    __shared__ float  s_tot[Pn];
    __shared__ int    s_best;

    for (int l = tid; l < Ln; l += NTH) s_idx[l] = l;
    if (tid < LPB) {
        const int l = c * LPB + tid;
        s_xp[tid] = make_float4(xpred[((size_t)b * Ln + l) * 3 + 0],
                                xpred[((size_t)b * Ln + l) * 3 + 1],
                                xpred[((size_t)b * Ln + l) * 3 + 2], 0.0f);
    }
    __syncthreads();

    const float* xpb = xpred + (size_t)b * Ln * 3;
    const float* xnb = xnat  + (size_t)b * Ln * 3;

    #pragma unroll 1
    for (int g = 0; g < Gn; g++) {
        const int* ag = autom + g * Pn * Kn;
        const int  gb = g * Bn + b;

        // ---- per-group staging: current x_nat columns for this block ----
        if (tid < LPB) {
            const int j = s_idx[c * LPB + tid];
            s_xn[tid] = make_float4(xnb[j * 3 + 0], xnb[j * 3 + 1], xnb[j * 3 + 2], 0.0f);
        }

        // ---- lane-k constants in registers ----
        const int a0k = ag[lane];
        const float px = xpb[a0k * 3 + 0];
        const float py = xpb[a0k * 3 + 1];
        const float pz = xpb[a0k * 3 + 2];

        float nx[Pn], ny[Pn], nz[Pn];
        #pragma unroll
        for (int p = 0; p < Pn; p++) {
            const int j = s_idx[ag[p * Kn + lane]];   // current row of a[p][k]
            nx[p] = xnb[j * 3 + 0];
            ny[p] = xnb[j * 3 + 1];
            nz[p] = xnb[j * 3 + 2];
        }
        __syncthreads();   // s_xn ready

        float acc[Pn];
        #pragma unroll
        for (int p = 0; p < Pn; p++) acc[p] = 0.0f;

        // ---- accumulate over this wave's l's: pure VALU inner loop ----
        const int il0 = wv * LPW;
        #pragma unroll 2
        for (int i = 0; i < LPW; i++) {
            const int il = il0 + i;
            const int l  = c * LPB + il;
            if (__ballot(a0k == l)) continue;     // colmask: l in base set (rare)

            const float4 q = s_xp[il];            // broadcast ds_read_b128
            const float4 m = s_xn[il];

            const float dx = px - q.x, dy = py - q.y, dz = pz - q.z;
            const float dp2 = dx * dx + dy * dy + dz * dz;

            #pragma unroll
            for (int p = 0; p < Pn; p++) {
                const float ex = nx[p] - m.x, ey = ny[p] - m.y, ez = nz[p] - m.z;
                const float dn2 = ex * ex + ey * ey + ez * ez;
                const float s  = __builtin_amdgcn_sqrtf(dp2 * dn2); // = dp*dn
                const float t  = (dp2 + dn2) - 2.0f * s;            // = (dp-dn)^2
                acc[p] += fminf(t, CLAMP_V);
            }
        }

        // ---- wave reduce on VALU pipe (DPP), result in lane 63 ----
        #pragma unroll
        for (int p = 0; p < Pn; p++) {
            const float v = wave_sum64(acc[p]);
            if (lane == 63) s_part[wv][p] = v;
        }
        __syncthreads();

        // ---- block reduce + one relaxed agent atomic per p ----
        if (tid < NWV * Pn) {
            const int p = tid >> 4;
            float v = s_part[tid & 15][p];
            v += __shfl_down(v, 8, 16);
            v += __shfl_down(v, 4, 16);
            v += __shfl_down(v, 2, 16);
            v += __shfl_down(v, 1, 16);
            if ((tid & 15) == 0)
                __hip_atomic_fetch_add(&drms[gb * Pn + p], v,
                                       __ATOMIC_RELAXED, __HIP_MEMORY_SCOPE_AGENT);
        }
        __syncthreads();   // drains vmcnt: adds acked before signal

        // ---- per-batch barrier: relaxed atomics only ----
        if (tid == 0) {
            __hip_atomic_fetch_add(&cnt[gb], 1, __ATOMIC_RELAXED, __HIP_MEMORY_SCOPE_AGENT);
            while (__hip_atomic_load(&cnt[gb], __ATOMIC_RELAXED, __HIP_MEMORY_SCOPE_AGENT) < BPB)
                __builtin_amdgcn_s_sleep(1);
        }
        __syncthreads();

        // ---- redundant argmin + private idx update ----
        if (tid < Pn)
            s_tot[tid] = __hip_atomic_load(&drms[gb * Pn + tid],
                                           __ATOMIC_RELAXED, __HIP_MEMORY_SCOPE_AGENT);
        __syncthreads();
        if (tid == 0) {
            float best = s_tot[0];
            int   bj   = 0;
            for (int p = 1; p < Pn; p++) {
                const float v = s_tot[p];
                if (v < best) { best = v; bj = p; }   // strict < == jnp.argmin tie rule
            }
            s_best = bj;
        }
        __syncthreads();

        const int bj = s_best;
        int oldv = 0;
        if (tid < Kn) oldv = s_idx[ag[bj * Kn + tid]];  // gather before scatter
        __syncthreads();
        if (tid < Kn) s_idx[ag[tid]] = oldv;
        __syncthreads();
    }

    // ---- epilogue: out = x_native[idx], mask[idx] ----
    const int l0 = c * LPB;
    if (tid < LPB * 3) {
        const int ll = tid / 3, coord = tid % 3;
        const int l  = l0 + ll;
        const int j  = s_idx[l];
        out_x[((size_t)b * Ln + l) * 3 + coord] = xnb[j * 3 + coord];
    } else if (tid < LPB * 4) {
        const int l = l0 + (tid - LPB * 3);
        const int j = s_idx[l];
        out_m[(size_t)b * Ln + l] = (float)mask_in[(size_t)b * Ln + j];
    }
}

// ---------------------------------------------------------------------------
extern "C" void kernel_launch(void* const* d_in, const int* in_sizes, int n_in,
                              void* d_out, int out_size, void* d_ws, size_t ws_size,
                              hipStream_t stream) {
    const float* xpred   = (const float*)d_in[0];  // (B,L,3) f32
    const float* xnat_in = (const float*)d_in[1];  // (B,L,3) f32
    const int*   mask_in = (const int*)  d_in[2];  // (B,L) bool -> int32
    const int*   autom   = (const int*)  d_in[3];  // (G,P,K) -> int32

    float* out_x = (float*)d_out;          // (B,L,3)
    float* out_m = out_x + Bn * Ln * 3;    // (B,L) as float 0/1

    float* drms = (float*)d_ws;                    // Gn*Bn*Pn floats
    int*   cnt  = (int*)(drms + Gn * Bn * Pn);     // Gn*Bn ints

    init_ws<<<1, 256, 0, stream>>>(drms, cnt);
    fused_kernel<<<Bn * BPB, NTH, 0, stream>>>(
        xpred, xnat_in, mask_in, autom, out_x, out_m, drms, cnt);
}

// Round 6
// 166.155 us; speedup vs baseline: 1.0971x; 1.0971x over previous
//
#include <hip/hip_runtime.h>
#include <math.h>

#define Bn 16
#define Ln 2048
#define Gn 8
#define Pn 8
#define Kn 64
#define CLAMP_V 15.0f

#define BPB 32              // blocks per batch
#define NTH 512             // threads per block = 8 waves
#define NWV (NTH / 64)      // 8 waves
#define LPB (Ln / BPB)      // 64 l's per block
#define LPW (LPB / NWV)     // 8 l's per wave
#define CNTPAD 16           // one 64B line per (g,b) barrier counter

// d_ws layout: part[Gn][Bn][BPB][Pn] floats (each slot written-once before read,
// no init needed), then cnt[Gn][Bn][CNTPAD] ints (zeroed by init_ws).

__global__ __launch_bounds__(256) void init_ws(int* __restrict__ cnt) {
    for (int j = threadIdx.x; j < Gn * Bn * CNTPAD; j += 256) cnt[j] = 0;
}

// wave64 sum via DPP (VALU pipe, no LDS). Total lands in lane 63.
__device__ __forceinline__ float wave_sum64(float x) {
#define DPP_ADD(ctrl) \
    x += __int_as_float(__builtin_amdgcn_update_dpp(0, __float_as_int(x), ctrl, 0xf, 0xf, true))
    DPP_ADD(0x111);  // row_shr:1
    DPP_ADD(0x112);  // row_shr:2
    DPP_ADD(0x114);  // row_shr:4
    DPP_ADD(0x118);  // row_shr:8
    DPP_ADD(0x142);  // row_bcast:15
    DPP_ADD(0x143);  // row_bcast:31
#undef DPP_ADD
    return x;
}

__device__ __forceinline__ float ld_rlx(const float* p) {
    return __hip_atomic_load(p, __ATOMIC_RELAXED, __HIP_MEMORY_SCOPE_AGENT);
}
__device__ __forceinline__ void st_rlx(float* p, float v) {
    __hip_atomic_store(p, v, __ATOMIC_RELAXED, __HIP_MEMORY_SCOPE_AGENT);
}

// ---------------------------------------------------------------------------
// Whole scan, one kernel. vs round 5:
//  * drms partials: per-block relaxed STORES to private slots (no RMW chain on
//    one cache line); every block re-reads all 32x8 partials post-barrier in
//    parallel and tree-reduces in LDS (redundant but latency-flat).
//  * cnt: padded to one cache line per (g,b) — no false sharing.
//  * next-group state (s_xn rows, lane constants) PREFETCHED before the
//    barrier with pre-update s_idx; post-barrier PATCH reloads only rows where
//    s_idx changed (~4/block) — post-barrier latency chain ~gone.
//  * BPB=32/NTH=512: 2 blocks per CU from DIFFERENT batches (b=blockIdx>>5,
//    blocks i and i+256 share a CU) — one computes while the other spins.
// Ordering stays fence-free: each wave's stores drain (vmcnt) at s_barrier
// before tid0's arrival add, so partials are acked when cnt hits BPB.
// ---------------------------------------------------------------------------
__global__ __launch_bounds__(NTH, 4) void fused_kernel(
    const float* __restrict__ xpred, const float* __restrict__ xnat,
    const int* __restrict__ mask_in, const int* __restrict__ autom,
    float* __restrict__ out_x, float* __restrict__ out_m,
    float* __restrict__ part, int* __restrict__ cnt) {

    const int tid  = threadIdx.x;
    const int lane = tid & 63;       // k
    const int wv   = tid >> 6;       // wave 0..7
    const int b    = blockIdx.x >> 5;         // batch (blocks i, i+256 differ)
    const int c    = blockIdx.x & (BPB - 1);  // chunk within batch

    __shared__ int    s_idx[Ln];          // private permutation: xnat row map
    __shared__ float4 s_xp[LPB];          // x_pred columns for this block
    __shared__ float4 s_xn[2][LPB];       // double-buffered x_nat columns
    __shared__ float  s_part[NWV][Pn];
    __shared__ float  s_red[BPB * Pn];    // cross-block partial gather
    __shared__ int    s_best;

    const float* xpb = xpred + (size_t)b * Ln * 3;
    const float* xnb = xnat  + (size_t)b * Ln * 3;

    // ---- prologue: identity idx; stage s_xp, s_xn[0]; g=0 lane constants ----
    for (int l = tid; l < Ln; l += NTH) s_idx[l] = l;
    if (tid < LPB) {
        const int l = c * LPB + tid;
        s_xp[tid]    = make_float4(xpb[l * 3 + 0], xpb[l * 3 + 1], xpb[l * 3 + 2], 0.0f);
        s_xn[0][tid] = make_float4(xnb[l * 3 + 0], xnb[l * 3 + 1], xnb[l * 3 + 2], 0.0f);
    }
    int   a0k = autom[lane];
    float px = xpb[a0k * 3 + 0], py = xpb[a0k * 3 + 1], pz = xpb[a0k * 3 + 2];
    float nx[Pn], ny[Pn], nz[Pn];
    #pragma unroll
    for (int p = 0; p < Pn; p++) {
        const int col = autom[p * Kn + lane];   // s_idx is identity at g=0
        nx[p] = xnb[col * 3 + 0];
        ny[p] = xnb[col * 3 + 1];
        nz[p] = xnb[col * 3 + 2];
    }
    __syncthreads();

    #pragma unroll 1
    for (int g = 0; g < Gn; g++) {
        const int* ag  = autom + g * Pn * Kn;
        const int* ag1 = autom + (g + 1) * Pn * Kn;   // safe: only read if g<7
        const int  cur = g & 1, nxt = cur ^ 1;
        const int  gb  = g * Bn + b;

        // ---- compute: pure VALU inner loop over this wave's l's ----
        float acc[Pn];
        #pragma unroll
        for (int p = 0; p < Pn; p++) acc[p] = 0.0f;

        const int il0 = wv * LPW;
        #pragma unroll 2
        for (int i = 0; i < LPW; i++) {
            const int il = il0 + i;
            const int l  = c * LPB + il;
            if (__ballot(a0k == l)) continue;     // colmask: l in base set (rare)

            const float4 q = s_xp[il];
            const float4 m = s_xn[cur][il];
            const float dx = px - q.x, dy = py - q.y, dz = pz - q.z;
            const float dp2 = dx * dx + dy * dy + dz * dz;

            #pragma unroll
            for (int p = 0; p < Pn; p++) {
                const float ex = nx[p] - m.x, ey = ny[p] - m.y, ez = nz[p] - m.z;
                const float dn2 = ex * ex + ey * ey + ez * ez;
                const float s  = __builtin_amdgcn_sqrtf(dp2 * dn2); // = dp*dn
                const float t  = (dp2 + dn2) - 2.0f * s;            // = (dp-dn)^2
                acc[p] += fminf(t, CLAMP_V);
            }
        }

        // ---- wave reduce (DPP), then block reduce, then ONE store per p ----
        #pragma unroll
        for (int p = 0; p < Pn; p++) {
            const float v = wave_sum64(acc[p]);
            if (lane == 63) s_part[wv][p] = v;
        }
        __syncthreads();
        if (tid < NWV * Pn) {               // 64 threads: p = tid>>3, w = tid&7
            const int p = tid >> 3;
            float v = s_part[tid & 7][p];
            v += __shfl_down(v, 4, 8);
            v += __shfl_down(v, 2, 8);
            v += __shfl_down(v, 1, 8);
            if ((tid & 7) == 0)
                st_rlx(&part[((size_t)gb * BPB + c) * Pn + p], v);  // plain store, no RMW
        }

        // ---- prefetch next group's state with PRE-update s_idx ----
        int   a0k1 = 0, colp[Pn], jold[Pn], prej = -1;
        float px1 = 0, py1 = 0, pz1 = 0;
        float nx1[Pn], ny1[Pn], nz1[Pn];
        if (g < Gn - 1) {
            a0k1 = ag1[lane];
            px1 = xpb[a0k1 * 3 + 0]; py1 = xpb[a0k1 * 3 + 1]; pz1 = xpb[a0k1 * 3 + 2];
            #pragma unroll
            for (int p = 0; p < Pn; p++) {
                colp[p] = ag1[p * Kn + lane];
                jold[p] = s_idx[colp[p]];
                nx1[p] = xnb[jold[p] * 3 + 0];
                ny1[p] = xnb[jold[p] * 3 + 1];
                nz1[p] = xnb[jold[p] * 3 + 2];
            }
            if (tid < LPB) {
                prej = s_idx[c * LPB + tid];
                s_xn[nxt][tid] = make_float4(xnb[prej * 3 + 0], xnb[prej * 3 + 1],
                                             xnb[prej * 3 + 2], 0.0f);
            }
        }
        __syncthreads();   // drains each wave's vmcnt -> partial stores acked

        // ---- per-batch barrier: padded counter, relaxed atomics only ----
        if (tid == 0) {
            int* cp = &cnt[gb * CNTPAD];
            __hip_atomic_fetch_add(cp, 1, __ATOMIC_RELAXED, __HIP_MEMORY_SCOPE_AGENT);
            while (__hip_atomic_load(cp, __ATOMIC_RELAXED, __HIP_MEMORY_SCOPE_AGENT) < BPB)
                __builtin_amdgcn_s_sleep(1);
        }
        __syncthreads();

        // ---- gather all 32x8 partials (parallel loads) + LDS tree reduce ----
        if (tid < BPB * Pn)                 // 256 threads: cc = tid>>3, p = tid&7
            s_red[tid] = ld_rlx(&part[((size_t)gb * BPB + (tid >> 3)) * Pn + (tid & 7)]);
        __syncthreads();
        #pragma unroll
        for (int off = (BPB * Pn) / 2; off >= Pn; off >>= 1) {   // 128..8
            if (tid < off) s_red[tid] += s_red[tid + off];
            __syncthreads();
        }
        if (tid == 0) {
            float best = s_red[0];
            int   bj   = 0;
            #pragma unroll
            for (int p = 1; p < Pn; p++) {
                const float v = s_red[p];
                if (v < best) { best = v; bj = p; }   // strict < == jnp.argmin tie rule
            }
            s_best = bj;
        }
        __syncthreads();

        // ---- private idx update ----
        const int bj = s_best;
        int oldv = 0;
        if (tid < Kn) oldv = s_idx[ag[bj * Kn + tid]];  // gather before scatter
        __syncthreads();
        if (tid < Kn) s_idx[ag[tid]] = oldv;
        __syncthreads();

        // ---- patch prefetched state where s_idx changed; adopt for g+1 ----
        if (g < Gn - 1) {
            if (tid < LPB) {
                const int j2 = s_idx[c * LPB + tid];
                if (j2 != prej)
                    s_xn[nxt][tid] = make_float4(xnb[j2 * 3 + 0], xnb[j2 * 3 + 1],
                                                 xnb[j2 * 3 + 2], 0.0f);
            }
            #pragma unroll
            for (int p = 0; p < Pn; p++) {
                const int j2 = s_idx[colp[p]];
                if (j2 != jold[p]) {
                    nx1[p] = xnb[j2 * 3 + 0];
                    ny1[p] = xnb[j2 * 3 + 1];
                    nz1[p] = xnb[j2 * 3 + 2];
                }
            }
            a0k = a0k1; px = px1; py = py1; pz = pz1;
            #pragma unroll
            for (int p = 0; p < Pn; p++) { nx[p] = nx1[p]; ny[p] = ny1[p]; nz[p] = nz1[p]; }
            __syncthreads();   // s_xn[nxt] visible to all waves before next compute
        }
    }

    // ---- epilogue: out = x_native[idx], mask[idx] ----
    const int l0 = c * LPB;
    if (tid < LPB * 3) {
        const int ll = tid / 3, coord = tid % 3;
        const int l  = l0 + ll;
        const int j  = s_idx[l];
        out_x[((size_t)b * Ln + l) * 3 + coord] = xnb[j * 3 + coord];
    } else if (tid < LPB * 4) {
        const int l = l0 + (tid - LPB * 3);
        const int j = s_idx[l];
        out_m[(size_t)b * Ln + l] = (float)mask_in[(size_t)b * Ln + j];
    }
}

// ---------------------------------------------------------------------------
extern "C" void kernel_launch(void* const* d_in, const int* in_sizes, int n_in,
                              void* d_out, int out_size, void* d_ws, size_t ws_size,
                              hipStream_t stream) {
    const float* xpred   = (const float*)d_in[0];  // (B,L,3) f32
    const float* xnat_in = (const float*)d_in[1];  // (B,L,3) f32
    const int*   mask_in = (const int*)  d_in[2];  // (B,L) bool -> int32
    const int*   autom   = (const int*)  d_in[3];  // (G,P,K) -> int32

    float* out_x = (float*)d_out;          // (B,L,3)
    float* out_m = out_x + Bn * Ln * 3;    // (B,L) as float 0/1

    float* part = (float*)d_ws;                          // Gn*Bn*BPB*Pn floats
    int*   cnt  = (int*)(part + Gn * Bn * BPB * Pn);     // Gn*Bn*CNTPAD ints

    init_ws<<<1, 256, 0, stream>>>(cnt);
    fused_kernel<<<Bn * BPB, NTH, 0, stream>>>(
        xpred, xnat_in, mask_in, autom, out_x, out_m, part, cnt);
}

// Round 9
// 161.545 us; speedup vs baseline: 1.1284x; 1.0285x over previous
//
#include <hip/hip_runtime.h>
#include <math.h>

#define Bn 16
#define Ln 2048
#define Gn 8
#define Pn 8
#define Kn 64
#define CLAMP_V 15.0f

#define BPB 32              // blocks per batch
#define NTH 512             // threads per block = 8 waves
#define NWV (NTH / 64)      // 8 waves
#define LPB (Ln / BPB)      // 64 l's per block
#define LPW (LPB / NWV)     // 8 l's per wave
#define CNTPAD 16           // one 64B line per (g,b) barrier counter

// d_ws layout: part[Gn][Bn][BPB][Pn] floats (each slot stored before it is
// ever loaded), then cnt[Gn][Bn][CNTPAD] ints (zeroed by init_ws).

__global__ __launch_bounds__(256) void init_ws(int* __restrict__ cnt) {
    for (int j = threadIdx.x; j < Gn * Bn * CNTPAD; j += 256) cnt[j] = 0;
}

// wave64 sum via DPP (VALU pipe, no LDS). Total lands in lane 63.
__device__ __forceinline__ float wave_sum64(float x) {
#define DPP_ADD(ctrl) \
    x += __int_as_float(__builtin_amdgcn_update_dpp(0, __float_as_int(x), ctrl, 0xf, 0xf, true))
    DPP_ADD(0x111);  // row_shr:1
    DPP_ADD(0x112);  // row_shr:2
    DPP_ADD(0x114);  // row_shr:4
    DPP_ADD(0x118);  // row_shr:8
    DPP_ADD(0x142);  // row_bcast:15
    DPP_ADD(0x143);  // row_bcast:31
#undef DPP_ADD
    return x;
}

// ds_swizzle pattern must be an integer constant expression -> template param.
template <int IMM>
__device__ __forceinline__ float swz_xor(float v) {
    return v + __int_as_float(__builtin_amdgcn_ds_swizzle(__float_as_int(v), IMM));
}
__device__ __forceinline__ float ld_rlx(const float* p) {
    return __hip_atomic_load(p, __ATOMIC_RELAXED, __HIP_MEMORY_SCOPE_AGENT);
}
__device__ __forceinline__ void st_rlx(float* p, float v) {
    __hip_atomic_store(p, v, __ATOMIC_RELAXED, __HIP_MEMORY_SCOPE_AGENT);
}

// ---------------------------------------------------------------------------
// vs round 8 (runtime abort):
//  * launch config reverted to round-6-proven __launch_bounds__(512,4) — no
//    waves_per_eu(4,4): its max-occupancy cap made residency an EXACT 512/512
//    fit, and the spin barrier deadlocks on any dispatch asymmetry. LDS cut
//    to ~9.3KB (s_idx ushort, s_stamp char) so packing slack is VGPR-bound
//    only (VGPR 64 -> 4 blocks/CU possible).
//  * anti-spill register reuse kept: prefetch overwrites the dead group-g
//    constants; epoch-stamp patch (s_stamp[row]=g) avoids colp/jold arrays.
//    Live VGPRs ~55-70 -> no scratch at the compiler's VGPR=64 choice.
//  * all cross-lane reduction is register-level (2x ds_swizzle xor + 1 cross-
//    half __shfl); round-8's same-wave LDS bounce without barrier was a race.
// Barrier protocol unchanged (validated rounds 4/6): relaxed agent atomics,
// vmcnt drained at the pre-arrival __syncthreads.
// ---------------------------------------------------------------------------
__global__ __launch_bounds__(NTH, 4) void fused_kernel(
    const float* __restrict__ xpred, const float* __restrict__ xnat,
    const int* __restrict__ mask_in, const int* __restrict__ autom,
    float* __restrict__ out_x, float* __restrict__ out_m,
    float* __restrict__ part, int* __restrict__ cnt) {

    const int tid  = threadIdx.x;
    const int lane = tid & 63;       // k
    const int wv   = tid >> 6;       // wave 0..7
    const int b    = blockIdx.x >> 5;         // batch
    const int c    = blockIdx.x & (BPB - 1);  // chunk within batch

    __shared__ unsigned short s_idx[Ln];    // 4KB: private permutation
    __shared__ signed char    s_stamp[Ln];  // 2KB: last group that updated row
    __shared__ float4         s_xp[LPB];    // 1KB: x_pred columns, this block
    __shared__ float4         s_xn[2][LPB]; // 2KB: dbuf x_nat columns
    __shared__ float          s_part[NWV][Pn];

    const float* xpb = xpred + (size_t)b * Ln * 3;
    const float* xnb = xnat  + (size_t)b * Ln * 3;

    // ---- prologue ----
    for (int l = tid; l < Ln; l += NTH) {
        s_idx[l]   = (unsigned short)l;
        s_stamp[l] = -1;
    }
    if (wv == 0) {
        const int l = c * LPB + lane;
        s_xp[lane]    = make_float4(xpb[l * 3 + 0], xpb[l * 3 + 1], xpb[l * 3 + 2], 0.0f);
    } else if (wv == 1) {
        const int l = c * LPB + lane;
        s_xn[0][lane] = make_float4(xnb[l * 3 + 0], xnb[l * 3 + 1], xnb[l * 3 + 2], 0.0f);
    }
    int   a0k = autom[lane];
    float px = xpb[a0k * 3 + 0], py = xpb[a0k * 3 + 1], pz = xpb[a0k * 3 + 2];
    float nx[Pn], ny[Pn], nz[Pn];
    #pragma unroll
    for (int p = 0; p < Pn; p++) {
        const int col = autom[p * Kn + lane];   // s_idx identity at g=0
        nx[p] = xnb[col * 3 + 0];
        ny[p] = xnb[col * 3 + 1];
        nz[p] = xnb[col * 3 + 2];
    }
    __syncthreads();

    #pragma unroll 1
    for (int g = 0; g < Gn; g++) {
        const int* ag  = autom + g * Pn * Kn;
        const int* ag1 = autom + (g + 1) * Pn * Kn;   // only read when g<7
        const int  cur = g & 1, nxt = cur ^ 1;
        const int  gb  = g * Bn + b;

        // ---- compute: pure VALU inner loop over this wave's l's ----
        float acc[Pn];
        #pragma unroll
        for (int p = 0; p < Pn; p++) acc[p] = 0.0f;

        const int il0 = wv * LPW;
        #pragma unroll 2
        for (int i = 0; i < LPW; i++) {
            const int il = il0 + i;
            const int l  = c * LPB + il;
            if (__ballot(a0k == l)) continue;     // colmask: l in base set (rare)

            const float4 q = s_xp[il];
            const float4 m = s_xn[cur][il];
            const float dx = px - q.x, dy = py - q.y, dz = pz - q.z;
            const float dp2 = dx * dx + dy * dy + dz * dz;

            #pragma unroll
            for (int p = 0; p < Pn; p++) {
                const float ex = nx[p] - m.x, ey = ny[p] - m.y, ez = nz[p] - m.z;
                const float dn2 = ex * ex + ey * ey + ez * ez;
                const float s  = __builtin_amdgcn_sqrtf(dp2 * dn2); // = dp*dn
                const float t  = (dp2 + dn2) - 2.0f * s;            // = (dp-dn)^2
                acc[p] += fminf(t, CLAMP_V);
            }
        }

        // ---- wave reduce (DPP, VALU pipe) ----
        #pragma unroll
        for (int p = 0; p < Pn; p++) {
            const float v = wave_sum64(acc[p]);
            if (lane == 63) s_part[wv][p] = v;
        }
        __syncthreads();

        // ---- wave 0: fold 8 waves x 8 p, store block partial (lanes 0..7) ----
        if (wv == 0) {
            float v = s_part[lane >> 3][lane & 7];   // lane = (q<<3)|p
            v = swz_xor<0x201F>(v);                  // fold q bit0 (xor 8)
            v = swz_xor<0x401F>(v);                  // fold q bit1 (xor 16)
            v += __shfl(v, lane + 32, 64);           // fold q bit2 (cross-half)
            if (lane < 8)
                st_rlx(&part[((size_t)gb * BPB + c) * Pn + lane], v);
        }

        // ---- prefetch next group's state into the SAME registers ----
        if (g < Gn - 1) {
            a0k = ag1[lane];
            px = xpb[a0k * 3 + 0]; py = xpb[a0k * 3 + 1]; pz = xpb[a0k * 3 + 2];
            #pragma unroll
            for (int p = 0; p < Pn; p++) {
                const int j = s_idx[ag1[p * Kn + lane]];   // pre-update map
                nx[p] = xnb[j * 3 + 0];
                ny[p] = xnb[j * 3 + 1];
                nz[p] = xnb[j * 3 + 2];
            }
            if (wv == 1) {
                const int j = s_idx[c * LPB + lane];
                s_xn[nxt][lane] = make_float4(xnb[j * 3 + 0], xnb[j * 3 + 1],
                                              xnb[j * 3 + 2], 0.0f);
            }
        }
        __syncthreads();   // drains vmcnt: partial store acked before arrival

        // ---- per-batch barrier: padded counter, relaxed atomics only ----
        if (tid == 0) {
            int* cp = &cnt[gb * CNTPAD];
            __hip_atomic_fetch_add(cp, 1, __ATOMIC_RELAXED, __HIP_MEMORY_SCOPE_AGENT);
            while (__hip_atomic_load(cp, __ATOMIC_RELAXED, __HIP_MEMORY_SCOPE_AGENT) < BPB)
                __builtin_amdgcn_s_sleep(1);
        }
        __syncthreads();

        // ---- post-barrier chain in wave 0, all register-level ----
        if (wv == 0) {
            const float* pg = part + (size_t)gb * BPB * Pn;   // 256 floats
            float v = ld_rlx(pg + lane)       + ld_rlx(pg + lane + 64)
                    + ld_rlx(pg + lane + 128) + ld_rlx(pg + lane + 192);
            v = swz_xor<0x201F>(v);
            v = swz_xor<0x401F>(v);
            v += __shfl(v, lane + 32, 64);   // lanes 0..7: total drms[p=lane]
            // all-lanes-uniform argmin over p (shfl from lanes 0..7)
            float best = __shfl(v, 0, 64);
            int   bj   = 0;
            #pragma unroll
            for (int p = 1; p < Pn; p++) {
                const float t = __shfl(v, p, 64);
                if (t < best) { best = t; bj = p; }  // strict < == argmin tie rule
            }
            // permutation update (gather then scatter, in-wave DS order)
            const unsigned short oldv = s_idx[ag[bj * Kn + lane]];
            s_idx[ag[lane]]   = oldv;
            s_stamp[ag[lane]] = (signed char)g;
        }
        __syncthreads();

        // ---- patch prefetched state where this group's update changed rows ----
        if (g < Gn - 1) {
            #pragma unroll
            for (int p = 0; p < Pn; p++) {
                const int col = ag1[p * Kn + lane];       // L1-hot reload
                if (s_stamp[col] == (signed char)g) {
                    const int j = s_idx[col];
                    nx[p] = xnb[j * 3 + 0];
                    ny[p] = xnb[j * 3 + 1];
                    nz[p] = xnb[j * 3 + 2];
                }
            }
            if (wv == 1) {
                const int l = c * LPB + lane;
                if (s_stamp[l] == (signed char)g) {
                    const int j = s_idx[l];
                    s_xn[nxt][lane] = make_float4(xnb[j * 3 + 0], xnb[j * 3 + 1],
                                                  xnb[j * 3 + 2], 0.0f);
                }
            }
            __syncthreads();   // s_xn[nxt] visible before next compute
        }
    }

    // ---- epilogue: out = x_native[idx], mask[idx] ----
    const int l0 = c * LPB;
    if (tid < LPB * 3) {
        const int ll = tid / 3, coord = tid % 3;
        const int l  = l0 + ll;
        const int j  = s_idx[l];
        out_x[((size_t)b * Ln + l) * 3 + coord] = xnb[j * 3 + coord];
    } else if (tid < LPB * 4) {
        const int l = l0 + (tid - LPB * 3);
        const int j = s_idx[l];
        out_m[(size_t)b * Ln + l] = (float)mask_in[(size_t)b * Ln + j];
    }
}

// ---------------------------------------------------------------------------
extern "C" void kernel_launch(void* const* d_in, const int* in_sizes, int n_in,
                              void* d_out, int out_size, void* d_ws, size_t ws_size,
                              hipStream_t stream) {
    const float* xpred   = (const float*)d_in[0];  // (B,L,3) f32
    const float* xnat_in = (const float*)d_in[1];  // (B,L,3) f32
    const int*   mask_in = (const int*)  d_in[2];  // (B,L) bool -> int32
    const int*   autom   = (const int*)  d_in[3];  // (G,P,K) -> int32

    float* out_x = (float*)d_out;          // (B,L,3)
    float* out_m = out_x + Bn * Ln * 3;    // (B,L) as float 0/1

    float* part = (float*)d_ws;                          // Gn*Bn*BPB*Pn floats
    int*   cnt  = (int*)(part + Gn * Bn * BPB * Pn);     // Gn*Bn*CNTPAD ints

    init_ws<<<1, 256, 0, stream>>>(cnt);
    fused_kernel<<<Bn * BPB, NTH, 0, stream>>>(
        xpred, xnat_in, mask_in, autom, out_x, out_m, part, cnt);
}

// Round 10
// 135.975 us; speedup vs baseline: 1.3406x; 1.1881x over previous
//
#include <hip/hip_runtime.h>
#include <math.h>

#define Bn 16
#define Ln 2048
#define Gn 8
#define Pn 8
#define Kn 64
#define CLAMP_V 15.0f

#define BPB 32              // blocks per batch
#define NTH 512             // threads per block = 8 waves
#define NWV (NTH / 64)      // 8 waves
#define LPB (Ln / BPB)      // 64 l's per block
#define LPW (LPB / NWV)     // 8 l's per wave

// d_ws layout: part[Gn][Bn][BPB][Pn] qwords. Each qword = {magic(g) << 32 |
// f32 partial}. Written exactly once per call; harness poison (0xAAAA..)
// never matches magic, so NO init pass / counter / barrier flag is needed —
// the tagged partial IS the arrival signal (one coherence round trip).

#define MAGIC(g) (0x5EED0000u | (unsigned)(g))

// wave64 sum via DPP (VALU pipe, no LDS). Total lands in lane 63.
__device__ __forceinline__ float wave_sum64(float x) {
#define DPP_ADD(ctrl) \
    x += __int_as_float(__builtin_amdgcn_update_dpp(0, __float_as_int(x), ctrl, 0xf, 0xf, true))
    DPP_ADD(0x111);  // row_shr:1
    DPP_ADD(0x112);  // row_shr:2
    DPP_ADD(0x114);  // row_shr:4
    DPP_ADD(0x118);  // row_shr:8
    DPP_ADD(0x142);  // row_bcast:15
    DPP_ADD(0x143);  // row_bcast:31
#undef DPP_ADD
    return x;
}

// ds_swizzle pattern must be an integer constant expression -> template param.
template <int IMM>
__device__ __forceinline__ float swz_xor(float v) {
    return v + __int_as_float(__builtin_amdgcn_ds_swizzle(__float_as_int(v), IMM));
}
__device__ __forceinline__ unsigned long long ld_rlx64(const unsigned long long* p) {
    return __hip_atomic_load(p, __ATOMIC_RELAXED, __HIP_MEMORY_SCOPE_AGENT);
}
__device__ __forceinline__ void st_rlx64(unsigned long long* p, unsigned long long v) {
    __hip_atomic_store(p, v, __ATOMIC_RELAXED, __HIP_MEMORY_SCOPE_AGENT);
}

// ---------------------------------------------------------------------------
// vs round 9 (113us kernel, ~62us sync/idle): the 3 serial coherence round
// trips per group (partial stores drain -> counter RMW chain + spin -> partial
// re-load) become ONE: 8B atomic qwords {magic|float} double as data+flag;
// consumers poll the 256 qwords directly (4/lane in wave 0) and already hold
// the data when the poll succeeds. Counter, init kernel, and second dispatch
// all deleted. Launch config unchanged from the round-9-proven one:
// __launch_bounds__(512,4), VGPR~48, LDS ~9.5KB -> ample residency slack for
// the spin protocol (grid 512 = 2 blocks/CU of a >=4-block capacity).
// ---------------------------------------------------------------------------
__global__ __launch_bounds__(NTH, 4) void fused_kernel(
    const float* __restrict__ xpred, const float* __restrict__ xnat,
    const int* __restrict__ mask_in, const int* __restrict__ autom,
    float* __restrict__ out_x, float* __restrict__ out_m,
    unsigned long long* __restrict__ part) {

    const int tid  = threadIdx.x;
    const int lane = tid & 63;       // k
    const int wv   = tid >> 6;       // wave 0..7
    const int b    = blockIdx.x >> 5;         // batch
    const int c    = blockIdx.x & (BPB - 1);  // chunk within batch

    __shared__ unsigned short s_idx[Ln];    // 4KB: private permutation
    __shared__ signed char    s_stamp[Ln];  // 2KB: last group that updated row
    __shared__ float4         s_xp[LPB];    // 1KB: x_pred columns, this block
    __shared__ float4         s_xn[2][LPB]; // 2KB: dbuf x_nat columns
    __shared__ float          s_part[NWV][Pn];

    const float* xpb = xpred + (size_t)b * Ln * 3;
    const float* xnb = xnat  + (size_t)b * Ln * 3;

    // ---- prologue ----
    for (int l = tid; l < Ln; l += NTH) {
        s_idx[l]   = (unsigned short)l;
        s_stamp[l] = -1;
    }
    if (wv == 0) {
        const int l = c * LPB + lane;
        s_xp[lane]    = make_float4(xpb[l * 3 + 0], xpb[l * 3 + 1], xpb[l * 3 + 2], 0.0f);
    } else if (wv == 1) {
        const int l = c * LPB + lane;
        s_xn[0][lane] = make_float4(xnb[l * 3 + 0], xnb[l * 3 + 1], xnb[l * 3 + 2], 0.0f);
    }
    int   a0k = autom[lane];
    float px = xpb[a0k * 3 + 0], py = xpb[a0k * 3 + 1], pz = xpb[a0k * 3 + 2];
    float nx[Pn], ny[Pn], nz[Pn];
    #pragma unroll
    for (int p = 0; p < Pn; p++) {
        const int col = autom[p * Kn + lane];   // s_idx identity at g=0
        nx[p] = xnb[col * 3 + 0];
        ny[p] = xnb[col * 3 + 1];
        nz[p] = xnb[col * 3 + 2];
    }
    __syncthreads();

    #pragma unroll 1
    for (int g = 0; g < Gn; g++) {
        const int* ag  = autom + g * Pn * Kn;
        const int* ag1 = autom + (g + 1) * Pn * Kn;   // only read when g<7
        const int  cur = g & 1, nxt = cur ^ 1;
        const int  gb  = g * Bn + b;
        unsigned long long* pg = part + (size_t)gb * (BPB * Pn);

        // ---- compute: pure VALU inner loop over this wave's l's ----
        float acc[Pn];
        #pragma unroll
        for (int p = 0; p < Pn; p++) acc[p] = 0.0f;

        const int il0 = wv * LPW;
        #pragma unroll 2
        for (int i = 0; i < LPW; i++) {
            const int il = il0 + i;
            const int l  = c * LPB + il;
            if (__ballot(a0k == l)) continue;     // colmask: l in base set (rare)

            const float4 q = s_xp[il];
            const float4 m = s_xn[cur][il];
            const float dx = px - q.x, dy = py - q.y, dz = pz - q.z;
            const float dp2 = dx * dx + dy * dy + dz * dz;

            #pragma unroll
            for (int p = 0; p < Pn; p++) {
                const float ex = nx[p] - m.x, ey = ny[p] - m.y, ez = nz[p] - m.z;
                const float dn2 = ex * ex + ey * ey + ez * ez;
                const float s  = __builtin_amdgcn_sqrtf(dp2 * dn2); // = dp*dn
                const float t  = (dp2 + dn2) - 2.0f * s;            // = (dp-dn)^2
                acc[p] += fminf(t, CLAMP_V);
            }
        }

        // ---- wave reduce (DPP, VALU pipe) ----
        #pragma unroll
        for (int p = 0; p < Pn; p++) {
            const float v = wave_sum64(acc[p]);
            if (lane == 63) s_part[wv][p] = v;
        }
        __syncthreads();

        // ---- wave 0: fold 8 waves x 8 p, publish tagged qwords ASAP ----
        if (wv == 0) {
            float v = s_part[lane >> 3][lane & 7];   // lane = (q<<3)|p
            v = swz_xor<0x201F>(v);                  // fold q bit0 (xor 8)
            v = swz_xor<0x401F>(v);                  // fold q bit1 (xor 16)
            v += __shfl(v, lane + 32, 64);           // fold q bit2 (cross-half)
            if (lane < 8)
                st_rlx64(&pg[c * Pn + lane],
                         ((unsigned long long)MAGIC(g) << 32) |
                         (unsigned long long)__float_as_uint(v));
        }

        // ---- prefetch next group's state into the SAME registers ----
        if (g < Gn - 1) {
            a0k = ag1[lane];
            px = xpb[a0k * 3 + 0]; py = xpb[a0k * 3 + 1]; pz = xpb[a0k * 3 + 2];
            #pragma unroll
            for (int p = 0; p < Pn; p++) {
                const int j = s_idx[ag1[p * Kn + lane]];   // pre-update map
                nx[p] = xnb[j * 3 + 0];
                ny[p] = xnb[j * 3 + 1];
                nz[p] = xnb[j * 3 + 2];
            }
            if (wv == 1) {
                const int j = s_idx[c * LPB + lane];
                s_xn[nxt][lane] = make_float4(xnb[j * 3 + 0], xnb[j * 3 + 1],
                                              xnb[j * 3 + 2], 0.0f);
            }
        }

        // ---- wave 0: poll all 32x8 tagged qwords (data arrives with flag),
        //      reduce, argmin, permutation update — all register-level ----
        if (wv == 0) {
            const unsigned magic = MAGIC(g);
            unsigned long long q0 = 0, q1 = 0, q2 = 0, q3 = 0;
            bool r0 = false, r1 = false, r2 = false, r3 = false;
            for (;;) {
                if (!r0) { q0 = ld_rlx64(pg + lane);       r0 = (unsigned)(q0 >> 32) == magic; }
                if (!r1) { q1 = ld_rlx64(pg + lane + 64);  r1 = (unsigned)(q1 >> 32) == magic; }
                if (!r2) { q2 = ld_rlx64(pg + lane + 128); r2 = (unsigned)(q2 >> 32) == magic; }
                if (!r3) { q3 = ld_rlx64(pg + lane + 192); r3 = (unsigned)(q3 >> 32) == magic; }
                if (__ballot(!(r0 && r1 && r2 && r3)) == 0ull) break;
                __builtin_amdgcn_s_sleep(1);
            }
            float v = __uint_as_float((unsigned)q0) + __uint_as_float((unsigned)q1)
                    + __uint_as_float((unsigned)q2) + __uint_as_float((unsigned)q3);
            v = swz_xor<0x201F>(v);          // fold c bit (lane bit 3)
            v = swz_xor<0x401F>(v);          // fold c bit (lane bit 4)
            v += __shfl(v, lane + 32, 64);   // fold c bit (lane bit 5)
            // lanes 0..7 hold total drms[p = lane]; argmin uniform via shfl
            float best = __shfl(v, 0, 64);
            int   bj   = 0;
            #pragma unroll
            for (int p = 1; p < Pn; p++) {
                const float t = __shfl(v, p, 64);
                if (t < best) { best = t; bj = p; }  // strict < == argmin tie rule
            }
            // permutation update (gather then scatter, in-wave DS order)
            const unsigned short oldv = s_idx[ag[bj * Kn + lane]];
            s_idx[ag[lane]]   = oldv;
            s_stamp[ag[lane]] = (signed char)g;
        }
        __syncthreads();

        // ---- patch prefetched state where this group's update changed rows ----
        if (g < Gn - 1) {
            #pragma unroll
            for (int p = 0; p < Pn; p++) {
                const int col = ag1[p * Kn + lane];       // L1-hot reload
                if (s_stamp[col] == (signed char)g) {
                    const int j = s_idx[col];
                    nx[p] = xnb[j * 3 + 0];
                    ny[p] = xnb[j * 3 + 1];
                    nz[p] = xnb[j * 3 + 2];
                }
            }
            if (wv == 1) {
                const int l = c * LPB + lane;
                if (s_stamp[l] == (signed char)g) {
                    const int j = s_idx[l];
                    s_xn[nxt][lane] = make_float4(xnb[j * 3 + 0], xnb[j * 3 + 1],
                                                  xnb[j * 3 + 2], 0.0f);
                }
            }
            __syncthreads();   // s_xn[nxt] visible before next compute
        }
    }

    // ---- epilogue: out = x_native[idx], mask[idx] ----
    const int l0 = c * LPB;
    if (tid < LPB * 3) {
        const int ll = tid / 3, coord = tid % 3;
        const int l  = l0 + ll;
        const int j  = s_idx[l];
        out_x[((size_t)b * Ln + l) * 3 + coord] = xnb[j * 3 + coord];
    } else if (tid < LPB * 4) {
        const int l = l0 + (tid - LPB * 3);
        const int j = s_idx[l];
        out_m[(size_t)b * Ln + l] = (float)mask_in[(size_t)b * Ln + j];
    }
}

// ---------------------------------------------------------------------------
extern "C" void kernel_launch(void* const* d_in, const int* in_sizes, int n_in,
                              void* d_out, int out_size, void* d_ws, size_t ws_size,
                              hipStream_t stream) {
    const float* xpred   = (const float*)d_in[0];  // (B,L,3) f32
    const float* xnat_in = (const float*)d_in[1];  // (B,L,3) f32
    const int*   mask_in = (const int*)  d_in[2];  // (B,L) bool -> int32
    const int*   autom   = (const int*)  d_in[3];  // (G,P,K) -> int32

    float* out_x = (float*)d_out;          // (B,L,3)
    float* out_m = out_x + Bn * Ln * 3;    // (B,L) as float 0/1

    unsigned long long* part = (unsigned long long*)d_ws;  // Gn*Bn*BPB*Pn qwords (256KB)

    fused_kernel<<<Bn * BPB, NTH, 0, stream>>>(
        xpred, xnat_in, mask_in, autom, out_x, out_m, part);
}